// Round 14
// baseline (933.866 us; speedup 1.0000x reference)
//
#include <hip/hip_runtime.h>
#include <hip/hip_bf16.h>
#include <hip/hip_fp16.h>

#define NN 50000
#define NE 400000
#define NBLK 196   // ceil(NN/256)
#define PST 544    // P row stride (1088 B = 64*17, breaks power-of-2 aliasing)
#define MTW 196    // ceil(NN/256) row-blocks for wave-tile GEMM

typedef unsigned short u16;
typedef unsigned int u32;
typedef __attribute__((ext_vector_type(8))) short short8;
typedef __attribute__((ext_vector_type(4))) float f32x4;
typedef __attribute__((ext_vector_type(4))) unsigned int u32x4;
typedef __attribute__((ext_vector_type(4))) unsigned short u16x4;
typedef __attribute__((ext_vector_type(2))) _Float16 h2;
typedef __attribute__((ext_vector_type(16))) unsigned int u32x16;

typedef __attribute__((address_space(1))) const void as1_void;
typedef __attribute__((address_space(3))) void as3_void;

static __device__ __forceinline__ float bf2f(u16 u) {
    return __uint_as_float(((u32)u) << 16);
}
static __device__ __forceinline__ float bf2f_lo(u32 u) {
    return __uint_as_float(u << 16);
}
static __device__ __forceinline__ float bf2f_hi(u32 u) {
    return __uint_as_float(u & 0xffff0000u);
}
static __device__ __forceinline__ u16 f2bf(float f) {
    u32 x = __float_as_uint(f);
    x += 0x7fffu + ((x >> 16) & 1u);
    return (u16)(x >> 16);
}
static __device__ __forceinline__ u32 packbf2(float a, float b) {
    return ((u32)f2bf(b) << 16) | (u32)f2bf(a);
}
static __device__ __forceinline__ u32 packh2(float a, float b) {
    return ((u32)__half_as_ushort(__float2half(b)) << 16) |
           (u32)__half_as_ushort(__float2half(a));
}
static __device__ __forceinline__ float fdot2u(u32 a, u32 b, float c) {
    return __builtin_amdgcn_fdot2(__builtin_bit_cast(h2, a),
                                  __builtin_bit_cast(h2, b), c, false);
}

static __device__ __forceinline__ void gload_lds16(const u16* g, u16* l) {
    __builtin_amdgcn_global_load_lds((as1_void*)g, (as3_void*)l, 16, 0, 0);
}

// ---------------------------------------------------------------------------
// Wave-independent bf16 GEMM: C[M,N] = A[M,K] @ Bt[N,K]^T (+bias)(relu).
// R14: the m97-style block GEMM ran ~10x off peak here because K<=512 gives
// only 4-8 K-iters/block and the per-iter __syncthreads drain (s_waitcnt
// vmcnt(0) lgkmcnt(0)) exposed the full staging latency (R13's BK=64 null
// proved barrier COUNT wasn't it; co-residency traded off 1:1).
// Structure: each WAVE owns a 64x64 tile; NO LDS, NO barriers. MFMA A/B
// fragments of a 64x64x32 step are exactly 16B/lane -> loaded directly
// global->register (8x global_load_dwordx4, asm), double-buffered with a
// counted vmcnt(8) wait (per-wave scoreboard; only vmem in the loop) +
// sched_barrier(0) so MFMAs can't hoist past the wait (rule #18). Operands
// are L2/L3-hot (A<=51MB in L3, B<=512KB in L2). K templated, fully
// unrolled; imm-free addressing via pointer bumps.
// ---------------------------------------------------------------------------
template<int K>
__global__ __launch_bounds__(256) void gemm_wv(
    const u16* __restrict__ A, int lda,
    const u16* __restrict__ Bt,
    u16* __restrict__ C, int ldc,
    int M,
    const float* __restrict__ bias,
    int relu)
{
    const int t = threadIdx.x;
    const int w = t >> 6;
    const int lane = t & 63;
    const int quad = lane >> 4;
    const int l15 = lane & 15;
    const int wrow = blockIdx.x * 256 + w * 64;   // wave's first output row
    const int tile_n = blockIdx.y * 64;

    // per-lane fragment stream pointers (advance 32 u16 per K-step)
    const u16* ap0; const u16* ap1; const u16* ap2; const u16* ap3;
    {
        int r0 = wrow + 0 * 16 + l15; if (r0 > M - 1) r0 = M - 1;
        int r1 = wrow + 1 * 16 + l15; if (r1 > M - 1) r1 = M - 1;
        int r2 = wrow + 2 * 16 + l15; if (r2 > M - 1) r2 = M - 1;
        int r3 = wrow + 3 * 16 + l15; if (r3 > M - 1) r3 = M - 1;
        ap0 = A + (size_t)r0 * lda + quad * 8;
        ap1 = A + (size_t)r1 * lda + quad * 8;
        ap2 = A + (size_t)r2 * lda + quad * 8;
        ap3 = A + (size_t)r3 * lda + quad * 8;
    }
    const u16* bp0 = Bt + (size_t)(tile_n + 0 * 16 + l15) * K + quad * 8;
    const u16* bp1 = Bt + (size_t)(tile_n + 1 * 16 + l15) * K + quad * 8;
    const u16* bp2 = Bt + (size_t)(tile_n + 2 * 16 + l15) * K + quad * 8;
    const u16* bp3 = Bt + (size_t)(tile_n + 3 * 16 + l15) * K + quad * 8;

    f32x4 acc[4][4];
#pragma unroll
    for (int r = 0; r < 4; ++r)
#pragma unroll
        for (int c = 0; c < 4; ++c)
            acc[r][c] = (f32x4){0.f, 0.f, 0.f, 0.f};

    constexpr int NK = K / 32;
    u32x4 a0[4], b0[4], a1[4], b1[4];

#define ISSUE8(AR, BR)                                                        \
    asm volatile("global_load_dwordx4 %0, %1, off" : "=v"(AR[0]) : "v"(ap0)); \
    asm volatile("global_load_dwordx4 %0, %1, off" : "=v"(AR[1]) : "v"(ap1)); \
    asm volatile("global_load_dwordx4 %0, %1, off" : "=v"(AR[2]) : "v"(ap2)); \
    asm volatile("global_load_dwordx4 %0, %1, off" : "=v"(AR[3]) : "v"(ap3)); \
    asm volatile("global_load_dwordx4 %0, %1, off" : "=v"(BR[0]) : "v"(bp0)); \
    asm volatile("global_load_dwordx4 %0, %1, off" : "=v"(BR[1]) : "v"(bp1)); \
    asm volatile("global_load_dwordx4 %0, %1, off" : "=v"(BR[2]) : "v"(bp2)); \
    asm volatile("global_load_dwordx4 %0, %1, off" : "=v"(BR[3]) : "v"(bp3)); \
    ap0 += 32; ap1 += 32; ap2 += 32; ap3 += 32;                               \
    bp0 += 32; bp1 += 32; bp2 += 32; bp3 += 32;

    // prologue: stage 0
    ISSUE8(a0, b0)

#pragma unroll
    for (int k = 0; k < NK; ++k) {
        u32x4 (&ca)[4] = (k & 1) ? a1 : a0;
        u32x4 (&cb)[4] = (k & 1) ? b1 : b0;
        u32x4 (&na)[4] = (k & 1) ? a0 : a1;
        u32x4 (&nb)[4] = (k & 1) ? b0 : b1;

        if (k + 1 < NK) {
            ISSUE8(na, nb)
            asm volatile("s_waitcnt vmcnt(8)" ::: "memory");
        } else {
            asm volatile("s_waitcnt vmcnt(0)" ::: "memory");
        }
        __builtin_amdgcn_sched_barrier(0);

#pragma unroll
        for (int r = 0; r < 4; ++r) {
            const short8 af = __builtin_bit_cast(short8, ca[r]);
#pragma unroll
            for (int c = 0; c < 4; ++c)
                acc[r][c] = __builtin_amdgcn_mfma_f32_16x16x32_bf16(
                    af, __builtin_bit_cast(short8, cb[c]), acc[r][c], 0, 0, 0);
        }
    }
#undef ISSUE8

#pragma unroll
    for (int r = 0; r < 4; ++r) {
#pragma unroll
        for (int c = 0; c < 4; ++c) {
            const int coln = tile_n + c * 16 + l15;
            const float bv = bias ? bias[coln] : 0.0f;
#pragma unroll
            for (int i = 0; i < 4; ++i) {
                const int row = wrow + r * 16 + quad * 4 + i;
                if (row < M) {
                    float v = acc[r][c][i] + bv;
                    if (relu) v = fmaxf(v, 0.f);
                    C[(size_t)row * ldc + coln] = f2bf(v);
                }
            }
        }
    }
}

// ---------------------------------------------------------------------------
// Fused edge message + mean aggregation. ONE wave per node, 256 cols
// (4 cols/lane as 2 packed-bf16 u32). R9 VERBATIM — proven 95us/63%occ.
// R11/R12 A/B: hand pipeline + fences strictly worse; keep this body.
// P rows [Ps(256)|Pd(256)], stride PST. agg -> Z[:,0:256] (stride 512).
// ---------------------------------------------------------------------------
__global__ __launch_bounds__(256) void edge_agg_fused(
    const u16* __restrict__ P,
    const u32* __restrict__ eattr_p32,
    const u32* __restrict__ WePk,
    const int* __restrict__ row_start,
    const int* __restrict__ src_perm,
    const float* __restrict__ inv_deg,
    u16* __restrict__ aggZ)
{
    __shared__ u32 Wlds[4096];   // 16 KB: same linear layout as WePk

    const int t = threadIdx.x;
    {   // stage weights: 4 rounds x (4 waves x 64 lanes x 16 B) = 16 KB
        const u16* Wg = (const u16*)WePk;
        u16* Wl = (u16*)Wlds;
        const int wv = t >> 6;
        const int ln = t & 63;
#pragma unroll
        for (int r = 0; r < 4; ++r)
            gload_lds16(Wg + r * 2048 + wv * 512 + ln * 8,
                        Wl + r * 2048 + wv * 512);
    }
    __syncthreads();

    const int node = (int)((blockIdx.x * 256 + t) >> 6);
    const int lane = t & 63;
    const int c4 = lane * 4;            // first of this lane's 4 cols
    if (node >= NN) return;             // grid exact; after barrier

    const uint2 pdu = *(const uint2*)(P + (size_t)node * PST + 256 + c4);
    const float pb0 = bf2f_lo(pdu.x), pb1 = bf2f_hi(pdu.x);
    const float pb2 = bf2f_lo(pdu.y), pb3 = bf2f_hi(pdu.y);

    float acc0 = 0.f, acc1 = 0.f, acc2 = 0.f, acc3 = 0.f;
    const int s0r = row_start[node], s1r = row_start[node + 1];

    if (s1r > s0r) {
        const int jlast = s1r - 1;
        const unsigned long long ebase =
            (unsigned long long)(uintptr_t)eattr_p32;
        const u32 voff = (u32)(c4 * 2);   // byte offset of lane's cols in a P row

        // src indices for the first trip (scalar loads, compiler-managed)
        int ssA = src_perm[__builtin_amdgcn_readfirstlane(s0r)];
        int ssB = src_perm[__builtin_amdgcn_readfirstlane(
            (s0r + 1 < jlast) ? s0r + 1 : jlast)];

        for (int j = s0r; j < s1r; j += 2) {
            // ps gathers for THIS trip: issued now, consumed after the dots
            const u16* rowpA = P + (size_t)ssA * PST;
            const u16* rowpB = P + (size_t)ssB * PST;
            uint2 psA, psB;
            asm volatile("global_load_dwordx2 %0, %1, %2"
                         : "=v"(psA) : "v"(voff), "s"(rowpA));
            asm volatile("global_load_dwordx2 %0, %1, %2"
                         : "=v"(psB) : "v"(voff), "s"(rowpB));

            // eattr rows for both edges -> SGPR tuples (scalar pipe)
            const u32 offA = (u32)__builtin_amdgcn_readfirstlane(j) << 6;
            const u32 offB = (u32)__builtin_amdgcn_readfirstlane(
                (j + 1 < jlast) ? j + 1 : jlast) << 6;
            u32x16 ea, eb;
            asm volatile("s_load_dwordx16 %0, %2, %3\n\t"
                         "s_load_dwordx16 %1, %2, %4"
                         : "=s"(ea), "=s"(eb)
                         : "s"(ebase), "s"(offA), "s"(offB));

            // prefetch next trip's src indices under the same lgkm wait
            const int jA2 = (j + 2 < jlast) ? j + 2 : jlast;
            const int jB2 = (j + 3 < jlast) ? j + 3 : jlast;
            int ssA_n = src_perm[__builtin_amdgcn_readfirstlane(jA2)];
            int ssB_n = src_perm[__builtin_amdgcn_readfirstlane(jB2)];

            asm volatile("s_waitcnt lgkmcnt(0)" ::: "memory");
            __builtin_amdgcn_sched_barrier(0);

            float qA0 = pb0, qA1 = pb1, qA2 = pb2, qA3 = pb3;
            float qB0 = pb0, qB1 = pb1, qB2 = pb2, qB3 = pb3;
#pragma unroll
            for (int kp = 0; kp < 16; ++kp) {
                uint4 wk = *(const uint4*)(Wlds + kp * 256 + c4);
                qA0 = fdot2u(ea[kp], wk.x, qA0);
                qA1 = fdot2u(ea[kp], wk.y, qA1);
                qA2 = fdot2u(ea[kp], wk.z, qA2);
                qA3 = fdot2u(ea[kp], wk.w, qA3);
                qB0 = fdot2u(eb[kp], wk.x, qB0);
                qB1 = fdot2u(eb[kp], wk.y, qB1);
                qB2 = fdot2u(eb[kp], wk.z, qB2);
                qB3 = fdot2u(eb[kp], wk.w, qB3);
            }

            // ps must have landed (only vmem in loop = our 2 asm loads)
            asm volatile("s_waitcnt vmcnt(0)" ::: "memory");
            __builtin_amdgcn_sched_barrier(0);

            acc0 += fmaxf(qA0 + bf2f_lo(psA.x), 0.f);
            acc1 += fmaxf(qA1 + bf2f_hi(psA.x), 0.f);
            acc2 += fmaxf(qA2 + bf2f_lo(psA.y), 0.f);
            acc3 += fmaxf(qA3 + bf2f_hi(psA.y), 0.f);
            const float mB = (j + 1 < s1r) ? 1.0f : 0.0f;
            acc0 = fmaf(mB, fmaxf(qB0 + bf2f_lo(psB.x), 0.f), acc0);
            acc1 = fmaf(mB, fmaxf(qB1 + bf2f_hi(psB.x), 0.f), acc1);
            acc2 = fmaf(mB, fmaxf(qB2 + bf2f_lo(psB.y), 0.f), acc2);
            acc3 = fmaf(mB, fmaxf(qB3 + bf2f_hi(psB.y), 0.f), acc3);

            ssA = ssA_n;
            ssB = ssB_n;
        }
    }

    const float idg = inv_deg[node];
    uint2 outv;
    outv.x = packbf2(acc0 * idg, acc1 * idg);
    outv.y = packbf2(acc2 * idg, acc3 * idg);
    *(uint2*)(aggZ + (size_t)node * 512 + c4) = outv;
}

// out[node] = dot(h4[node,:], h2w) + h2b  — one wave per node; h4 in Z[:,0:256]
__global__ __launch_bounds__(256) void head_out(
    const u16* __restrict__ h4Z,
    const float* __restrict__ h2w,
    const float* __restrict__ h2b,
    float* __restrict__ out)
{
    const int node = (int)((blockIdx.x * 256 + threadIdx.x) >> 6);
    const int lane = threadIdx.x & 63;
    if (node >= NN) return;
    const int col = lane * 4;
    u16x4 hv = *(const u16x4*)(h4Z + (size_t)node * 512 + col);
    float4 wv = *(const float4*)(h2w + col);
    float s = bf2f(hv[0]) * wv.x + bf2f(hv[1]) * wv.y +
              bf2f(hv[2]) * wv.z + bf2f(hv[3]) * wv.w;
    for (int off = 32; off > 0; off >>= 1)
        s += __shfl_down(s, off, 64);
    if (lane == 0) out[node] = s + h2b[0];
}

// ---------------- setup kernels ----------------
__global__ void zero_int(int* p, int n) {
    int i = blockIdx.x * 256 + threadIdx.x;
    if (i < n) p[i] = 0;
}

__global__ void hist_k(const int* __restrict__ ei, int* __restrict__ deg) {
    int e = blockIdx.x * 256 + threadIdx.x;
    if (e < NE) atomicAdd(&deg[ei[NE + e]], 1);
}

__global__ __launch_bounds__(256) void block_sum_k(const int* __restrict__ deg,
                                                   int* __restrict__ bsum) {
    __shared__ int sm[4];
    const int i = blockIdx.x * 256 + threadIdx.x;
    int v = (i < NN) ? deg[i] : 0;
    for (int off = 32; off > 0; off >>= 1)
        v += __shfl_down(v, off, 64);
    const int lane = threadIdx.x & 63;
    const int w = threadIdx.x >> 6;
    if (lane == 0) sm[w] = v;
    __syncthreads();
    if (threadIdx.x == 0)
        bsum[blockIdx.x] = sm[0] + sm[1] + sm[2] + sm[3];
}

__global__ __launch_bounds__(256) void scan_block_k(const int* __restrict__ bsum,
                                                    int* __restrict__ boff,
                                                    int* __restrict__ row_start) {
    __shared__ int sm[256];
    const int tid = threadIdx.x;
    int v = (tid < NBLK) ? bsum[tid] : 0;
    sm[tid] = v;
    __syncthreads();
    for (int o = 1; o < 256; o <<= 1) {
        int tv = (tid >= o) ? sm[tid - o] : 0;
        __syncthreads();
        sm[tid] += tv;
        __syncthreads();
    }
    if (tid < NBLK) boff[tid] = sm[tid] - v;  // exclusive
    if (tid == NBLK - 1) row_start[NN] = sm[tid];
}

__global__ __launch_bounds__(256) void writeback_k(const int* __restrict__ deg,
                                                   const int* __restrict__ boff,
                                                   int* __restrict__ row_start,
                                                   int* __restrict__ cursor,
                                                   float* __restrict__ inv_deg) {
    __shared__ int sm[256];
    const int tid = threadIdx.x;
    const int i = blockIdx.x * 256 + tid;
    int v = (i < NN) ? deg[i] : 0;
    sm[tid] = v;
    __syncthreads();
    for (int o = 1; o < 256; o <<= 1) {
        int tv = (tid >= o) ? sm[tid - o] : 0;
        __syncthreads();
        sm[tid] += tv;
        __syncthreads();
    }
    if (i < NN) {
        const int rs = boff[blockIdx.x] + sm[tid] - v;
        row_start[i] = rs;
        cursor[i]    = rs;
        inv_deg[i]   = 1.0f / fmaxf((float)v, 1.0f);
    }
}

__global__ void scatter_k(const int* __restrict__ ei, const float* __restrict__ eattr,
                          int* __restrict__ cursor, int* __restrict__ src_perm,
                          u32* __restrict__ eattr_p32) {
    int e = blockIdx.x * 256 + threadIdx.x;
    if (e >= NE) return;
    int s = ei[e], d = ei[NE + e];
    int pos = atomicAdd(&cursor[d], 1);
    src_perm[pos] = s;
    const float* sr = eattr + (size_t)e * 32;
    u32 pk[16];
#pragma unroll
    for (int j = 0; j < 16; ++j)
        pk[j] = packh2(sr[2 * j], sr[2 * j + 1]);
    uint4* dr = (uint4*)(eattr_p32 + (size_t)pos * 16);
    dr[0] = (uint4){pk[0], pk[1], pk[2], pk[3]};
    dr[1] = (uint4){pk[4], pk[5], pk[6], pk[7]};
    dr[2] = (uint4){pk[8], pk[9], pk[10], pk[11]};
    dr[3] = (uint4){pk[12], pk[13], pk[14], pk[15]};
}

// P-GEMM bias: [512] f32 per layer = [0(256) | eb(256)]
__global__ void bias_build(const float* __restrict__ e0b,
                           const float* __restrict__ eb1,
                           const float* __restrict__ eb2,
                           float* __restrict__ dst) {
    int i = blockIdx.x * 256 + threadIdx.x;
    if (i >= 1536) return;
    int l = i >> 9, c = i & 511;
    const float* s = (l == 0) ? e0b : (l == 1) ? eb1 : eb2;
    dst[i] = (c < 256) ? 0.f : s[c - 256];
}

// jobs: tr=1: dst[n*dstride+k] = bf16(src[k*256+n]), n in 0..255, k in 0..K-1
//       tr=2: We pack u32: dst32[kp*256+c] = packh2(src[2kp*256+c], src[(2kp+1)*256+c])
struct TJob { const float* src; u16* dst; int K; int ksh; int tr; int dstride; };
struct TJobs { TJob j[16]; };

__global__ void transpose_k(TJobs jobs) {
    TJob jb = jobs.j[blockIdx.y];
    int idx = blockIdx.x * 256 + threadIdx.x;
    if (idx >= (jb.K << 8)) return;
    if (jb.tr == 1) {
        int n = idx >> jb.ksh;
        int k = idx & (jb.K - 1);
        jb.dst[n * jb.dstride + k] = f2bf(jb.src[k * 256 + n]);
    } else {
        int kp = idx >> 8;
        int c = idx & 255;
        ((u32*)jb.dst)[idx] = packh2(jb.src[(2 * kp) * 256 + c],
                                     jb.src[(2 * kp + 1) * 256 + c]);
    }
}

// x (f32 [NN,128]) -> Z[:,256:384] bf16 (row stride 512)
__global__ void cvt_x(const float* __restrict__ src, u16* __restrict__ Z) {
    int i = blockIdx.x * 256 + threadIdx.x;
    if (i >= NN * 128) return;
    int n = i >> 7, c = i & 127;
    Z[(size_t)n * 512 + 256 + c] = f2bf(src[i]);
}

// ---------------------------------------------------------------------------
extern "C" void kernel_launch(void* const* d_in, const int* in_sizes, int n_in,
                              void* d_out, int out_size, void* d_ws, size_t ws_size,
                              hipStream_t stream) {
    const float* x     = (const float*)d_in[0];
    const int*   ei    = (const int*)d_in[1];
    const float* eattr = (const float*)d_in[2];
    const float* e0_w  = (const float*)d_in[3];
    const float* e0_b  = (const float*)d_in[4];
    const float* n0_w  = (const float*)d_in[5];
    const float* n0_b  = (const float*)d_in[6];
    const float* e_w   = (const float*)d_in[7];
    const float* e_b   = (const float*)d_in[8];
    const float* n_w   = (const float*)d_in[9];
    const float* n_b   = (const float*)d_in[10];
    const float* h1_w  = (const float*)d_in[11];
    const float* h1_b  = (const float*)d_in[12];
    const float* h2_w  = (const float*)d_in[13];
    const float* h2_b  = (const float*)d_in[14];
    float* out = (float*)d_out;
    (void)in_sizes; (void)n_in; (void)out_size; (void)ws_size;

    char* base = (char*)d_ws;
    size_t off = 0;
    auto alloc = [&](size_t nbytes) -> void* {
        void* p = base + off;
        off += (nbytes + 255) & ~(size_t)255;
        return p;
    };

    int*   deg       = (int*)alloc(NN * 4);
    int*   row_start = (int*)alloc((NN + 1) * 4);
    int*   cursor    = (int*)alloc(NN * 4);
    float* invdeg    = (float*)alloc(NN * 4);
    int*   bsum      = (int*)alloc(NBLK * 4);
    int*   boff      = (int*)alloc(NBLK * 4);
    int*   src_perm  = (int*)alloc(NE * 4);
    u32*   eattr_p32 = (u32*)alloc((size_t)NE * 16 * 4);
    u16*   WcatT0    = (u16*)alloc(512 * 128 * 2);
    u16*   WcatT1    = (u16*)alloc(512 * 256 * 2);
    u16*   WcatT2    = (u16*)alloc(512 * 256 * 2);
    u32*   WePk0     = (u32*)alloc(16 * 256 * 4);
    u32*   WePk1     = (u32*)alloc(16 * 256 * 4);
    u32*   WePk2     = (u32*)alloc(16 * 256 * 4);
    u16*   BcatT0    = (u16*)alloc(256 * 384 * 2);
    u16*   BcatT1    = (u16*)alloc(256 * 512 * 2);
    u16*   BcatT2    = (u16*)alloc(256 * 512 * 2);
    u16*   H1T       = (u16*)alloc(256 * 256 * 2);
    float* bias512   = (float*)alloc(3 * 512 * 4);
    u16*   P         = (u16*)alloc((size_t)NN * PST * 2);
    u16*   Z0        = (u16*)alloc((size_t)NN * 512 * 2);
    u16*   Z1        = (u16*)alloc((size_t)NN * 512 * 2);

    // ---- CSR build + weight prep ----
    zero_int<<<(NN + 255) / 256, 256, 0, stream>>>(deg, NN);
    hist_k<<<(NE + 255) / 256, 256, 0, stream>>>(ei, deg);
    block_sum_k<<<NBLK, 256, 0, stream>>>(deg, bsum);
    scan_block_k<<<1, 256, 0, stream>>>(bsum, boff, row_start);
    writeback_k<<<NBLK, 256, 0, stream>>>(deg, boff, row_start, cursor, invdeg);
    scatter_k<<<(NE + 255) / 256, 256, 0, stream>>>(ei, eattr, cursor, src_perm, eattr_p32);
    bias_build<<<6, 256, 0, stream>>>(e0_b, e_b, e_b + 256, bias512);

    const float* ew2 = e_w + 544 * 256;
    const float* nw2 = n_w + 512 * 256;

    TJobs tj;
    auto setj = [&](int i, const float* s, void* d, int K, int tr, int dstride) {
        tj.j[i].src = s; tj.j[i].dst = (u16*)d; tj.j[i].K = K; tj.j[i].tr = tr;
        tj.j[i].dstride = dstride;
        tj.j[i].ksh = (K == 256) ? 8 : (K == 128 ? 7 : 5);
    };
    // P-GEMM weights: WcatT[n(512)][K] = [Ws rows | Wd rows] transposed
    setj(0,  e0_w,             WcatT0,             128, 1, 128);
    setj(1,  e0_w + 128 * 256, WcatT0 + 256 * 128, 128, 1, 128);
    setj(2,  e_w,              WcatT1,             256, 1, 256);
    setj(3,  e_w + 256 * 256,  WcatT1 + 256 * 256, 256, 1, 256);
    setj(4,  ew2,              WcatT2,             256, 1, 256);
    setj(5,  ew2 + 256 * 256,  WcatT2 + 256 * 256, 256, 1, 256);
    // node-GEMM weights: BcatT[n(256)][k] = [nbot(k<256) | ntop]
    setj(6,  n0_w + 128 * 256, BcatT0,             256, 1, 384);
    setj(7,  n0_w,             BcatT0 + 256,       128, 1, 384);
    setj(8,  n_w + 256 * 256,  BcatT1,             256, 1, 512);
    setj(9,  n_w,              BcatT1 + 256,       256, 1, 512);
    setj(10, nw2 + 256 * 256,  BcatT2,             256, 1, 512);
    setj(11, nw2,              BcatT2 + 256,       256, 1, 512);
    setj(12, h1_w,             H1T,                256, 1, 256);
    // edge-attr weights, packed f16 pairs
    setj(13, e0_w + 256 * 256, WePk0,              16,  2, 0);
    setj(14, e_w + 512 * 256,  WePk1,              16,  2, 0);
    setj(15, ew2 + 512 * 256,  WePk2,              16,  2, 0);
    transpose_k<<<dim3(256, 16), 256, 0, stream>>>(tj);

    cvt_x<<<(NN * 128 + 255) / 256, 256, 0, stream>>>(x, Z0);

    const int AGG_GRID = NN / 4;      // 1 wave/node, 4 waves/block = 12500
    u16* WcatT[3] = {WcatT0, WcatT1, WcatT2};
    u32* WePk[3]  = {WePk0, WePk1, WePk2};
    u16* BcatT[3] = {BcatT0, BcatT1, BcatT2};
    const float* nbs[3] = {n0_b, n_b, n_b + 256};
    u16* Zin[3]  = {Z0, Z1, Z0};
    u16* Zout[3] = {Z1, Z0, Z1};
    const int kin[3]   = {128, 256, 256};
    const int knode[3] = {384, 512, 512};

    auto launch_gemm = [&](const u16* A, int lda, const u16* Bt, u16* C, int ldc,
                           int K, int N, const float* bias, int relu) {
        dim3 g(MTW, N / 64);
        switch (K) {
            case 128: gemm_wv<128><<<g, 256, 0, stream>>>(A, lda, Bt, C, ldc, NN, bias, relu); break;
            case 256: gemm_wv<256><<<g, 256, 0, stream>>>(A, lda, Bt, C, ldc, NN, bias, relu); break;
            case 384: gemm_wv<384><<<g, 256, 0, stream>>>(A, lda, Bt, C, ldc, NN, bias, relu); break;
            default:  gemm_wv<512><<<g, 256, 0, stream>>>(A, lda, Bt, C, ldc, NN, bias, relu); break;
        }
    };

    for (int l = 0; l < 3; ++l) {
        // P = h @ [Ws | Wd] + [0|eb]  -> [NN, 512] (stride PST)
        launch_gemm(Zin[l] + 256, 512, WcatT[l], P, PST, kin[l], 512,
                    bias512 + l * 512, 0);
        // agg = mean_dst relu(Ps[src] + Pd[dst] + eattr@We)
        edge_agg_fused<<<AGG_GRID, 256, 0, stream>>>(P, eattr_p32, WePk[l], row_start,
                                                     src_perm, invdeg, Zin[l]);
        // h' = relu([agg | h] @ [nbot; ntop] + nb)
        launch_gemm(Zin[l], 512, BcatT[l], Zout[l] + 256, 512, knode[l], 256,
                    nbs[l], 1);
    }
    // head: h4 = relu(h3 @ h1_w + h1_b) -> Z1[:,0:256]; out = h4 @ h2_w + h2_b
    launch_gemm(Z1 + 256, 512, H1T, Z1, 512, 256, 256, h1_b, 1);
    head_out<<<NN / 4, 256, 0, stream>>>(Z1, h2_w, h2_b, out);
}